// Round 1
// baseline (112.766 us; speedup 1.0000x reference)
//
#include <hip/hip_runtime.h>
#include <math.h>

// ---------------------------------------------------------------------------
// Refiner: 4 stages of {concat(h, resized ViT feature) -> 3x3 conv(769->1)
// -> ReLU -> BN -> 2x bilinear up}, then Linear(224,224) over last dim + sigmoid.
//
// Algebraic reduction: feature channels enter linearly through bilinear
// resize, so pre-reduce  B[s][t][u][v] = sum_c conv_w[1+c][t] * f14[c][u][v]
// (14x14 per tap per stage). Each stage's feature term is then a single
// bilinear sample of B. h-upsample is fused into the consumer kernel
// (BN is affine => commutes with bilinear resize).
//
// Bilinear (jax.image.resize / PyTorch align_corners=False, upsample):
//   src = (p + 0.5) / scale - 0.5, clamped to [0, in-1], 2-tap lerp.
// ---------------------------------------------------------------------------

#define BN_EPS 1e-5f

__device__ __forceinline__ float clampf(float x, float lo, float hi) {
    return fminf(fmaxf(x, lo), hi);
}

// WT[w*224 + o] = W[o*224 + w]
__global__ void transpose_W_kernel(const float* __restrict__ W, float* __restrict__ WT) {
    int idx = blockIdx.x * 256 + threadIdx.x;
    if (idx >= 224 * 224) return;
    int w = idx / 224, o = idx % 224;
    WT[idx] = W[o * 224 + w];
}

// B[s*1764 + t*196 + uv] = sum_{k=0..767} conv_w[(1+k)*9 + t] * fv[(3-s), 1+uv, k]
__global__ void compute_B_kernel(const float* __restrict__ fv,
                                 const float* __restrict__ conv_w,
                                 float* __restrict__ Bout) {
    int blk = blockIdx.x;          // 0..783
    int s = blk / 196;             // stage 0..3
    int uv = blk % 196;            // u*14+v
    int fidx = 3 - s;
    const float* fvrow = fv + ((size_t)fidx * 197 + 1 + uv) * 768;

    float part[9];
#pragma unroll
    for (int t = 0; t < 9; ++t) part[t] = 0.f;

    for (int k = threadIdx.x; k < 768; k += 256) {
        float fval = fvrow[k];
        const float* w = conv_w + (size_t)(1 + k) * 9;
#pragma unroll
        for (int t = 0; t < 9; ++t) part[t] += fval * w[t];
    }

    // wave (64-lane) shuffle reduction, then cross-wave via LDS
#pragma unroll
    for (int t = 0; t < 9; ++t) {
#pragma unroll
        for (int off = 32; off > 0; off >>= 1)
            part[t] += __shfl_down(part[t], off, 64);
    }
    __shared__ float red[4][9];
    int wave = threadIdx.x >> 6, lane = threadIdx.x & 63;
    if (lane == 0) {
#pragma unroll
        for (int t = 0; t < 9; ++t) red[wave][t] = part[t];
    }
    __syncthreads();
    if (threadIdx.x < 9) {
        int t = threadIdx.x;
        float v = red[0][t] + red[1][t] + red[2][t] + red[3][t];
        Bout[s * 1764 + t * 196 + uv] = v;
    }
}

// One refinement stage at resolution H (output yout[H*H], post-ReLU+BN).
// hsrc: previous post-BN map at srcH (doUp=1: sample with 2x bilinear up;
//       doUp=0: direct read, stage 1 where hsrc = x[14x14]).
// B: this stage's 9 x 14 x 14 pre-reduced feature maps.
__global__ void stage_kernel(const float* __restrict__ hsrc, int srcH, int doUp,
                             const float* __restrict__ B,
                             const float* __restrict__ conv_w,
                             const float* __restrict__ conv_b,
                             const float* __restrict__ bng, const float* __restrict__ bnb,
                             const float* __restrict__ bnm, const float* __restrict__ bnv,
                             float* __restrict__ yout, int H) {
    int idx = blockIdx.x * blockDim.x + threadIdx.x;
    if (idx >= H * H) return;
    int i = idx / H, j = idx % H;

    float featScale = 14.0f / (float)H;   // output px -> 14x14 source coords
    float srcMax = (float)(srcH - 1);

    float acc = conv_b[0];

#pragma unroll
    for (int a = 0; a < 3; ++a) {
        int p = i + a - 1;
        if (p < 0 || p >= H) continue;     // SAME zero padding: whole tap is 0
        // feature row sample params
        float fy = clampf(((float)p + 0.5f) * featScale - 0.5f, 0.f, 13.f);
        int by0 = (int)fy; float bfy = fy - (float)by0; int by1 = min(by0 + 1, 13);
        // h row sample params
        float hy = clampf(((float)p + 0.5f) * 0.5f - 0.5f, 0.f, srcMax);
        int hy0 = (int)hy; float fhy = hy - (float)hy0; int hy1 = min(hy0 + 1, srcH - 1);

#pragma unroll
        for (int bq = 0; bq < 3; ++bq) {
            int q = j + bq - 1;
            if (q < 0 || q >= H) continue;
            int t = a * 3 + bq;

            float fx = clampf(((float)q + 0.5f) * featScale - 0.5f, 0.f, 13.f);
            int bx0 = (int)fx; float bfx = fx - (float)bx0; int bx1 = min(bx0 + 1, 13);
            const float* Bt = B + t * 196;
            float bv = (1.f - bfy) * ((1.f - bfx) * Bt[by0 * 14 + bx0] + bfx * Bt[by0 * 14 + bx1])
                     + bfy         * ((1.f - bfx) * Bt[by1 * 14 + bx0] + bfx * Bt[by1 * 14 + bx1]);

            float hval;
            if (doUp) {
                float hx = clampf(((float)q + 0.5f) * 0.5f - 0.5f, 0.f, srcMax);
                int hx0 = (int)hx; float fhx = hx - (float)hx0; int hx1 = min(hx0 + 1, srcH - 1);
                hval = (1.f - fhy) * ((1.f - fhx) * hsrc[hy0 * srcH + hx0] + fhx * hsrc[hy0 * srcH + hx1])
                     + fhy         * ((1.f - fhx) * hsrc[hy1 * srcH + hx0] + fhx * hsrc[hy1 * srcH + hx1]);
            } else {
                hval = hsrc[p * srcH + q];
            }
            acc += conv_w[t] * hval + bv;
        }
    }

    float scale = bng[0] * rsqrtf(bnv[0] + BN_EPS);
    float shift = bnb[0] - bnm[0] * scale;
    float y = fmaxf(acc, 0.f) * scale + shift;
    yout[idx] = y;
}

// out[r*224+o] = sigmoid( sum_w up2(y4)[r,w] * W[o,w] + Wb[o] )
// 2x upsample of y4 (112x112) fused; W pre-transposed for coalesced reads.
#define RT 2
__global__ void final_kernel(const float* __restrict__ y4,
                             const float* __restrict__ WT,
                             const float* __restrict__ Wb,
                             float* __restrict__ out) {
    __shared__ float hrow[RT][224];
    int r0 = blockIdx.x * RT;

    for (int k = threadIdx.x; k < RT * 224; k += blockDim.x) {
        int rr = k / 224, w = k % 224;
        int r = r0 + rr;
        float hy = clampf(((float)r + 0.5f) * 0.5f - 0.5f, 0.f, 111.f);
        int y0 = (int)hy; float fy = hy - (float)y0; int y1 = min(y0 + 1, 111);
        float hx = clampf(((float)w + 0.5f) * 0.5f - 0.5f, 0.f, 111.f);
        int x0 = (int)hx; float fx = hx - (float)x0; int x1 = min(x0 + 1, 111);
        hrow[rr][w] = (1.f - fy) * ((1.f - fx) * y4[y0 * 112 + x0] + fx * y4[y0 * 112 + x1])
                    + fy         * ((1.f - fx) * y4[y1 * 112 + x0] + fx * y4[y1 * 112 + x1]);
    }
    __syncthreads();

    int o = threadIdx.x;
    if (o >= 224) return;
    float acc[RT];
#pragma unroll
    for (int rr = 0; rr < RT; ++rr) acc[rr] = Wb[o];

    for (int w = 0; w < 224; ++w) {
        float wt = WT[w * 224 + o];   // coalesced across threads
#pragma unroll
        for (int rr = 0; rr < RT; ++rr) acc[rr] += hrow[rr][w] * wt;
    }
#pragma unroll
    for (int rr = 0; rr < RT; ++rr) {
        float v = 1.f / (1.f + expf(-acc[rr]));
        out[(size_t)(r0 + rr) * 224 + o] = v;
    }
}

extern "C" void kernel_launch(void* const* d_in, const int* in_sizes, int n_in,
                              void* d_out, int out_size, void* d_ws, size_t ws_size,
                              hipStream_t stream) {
    const float* x      = (const float*)d_in[0];   // [14,14]
    const float* fv     = (const float*)d_in[1];   // [4,197,768]
    const float* conv_w = (const float*)d_in[2];   // [1,769,3,3]
    const float* conv_b = (const float*)d_in[3];   // [1]
    const float* bng    = (const float*)d_in[4];
    const float* bnb    = (const float*)d_in[5];
    const float* bnm    = (const float*)d_in[6];
    const float* bnv    = (const float*)d_in[7];
    const float* W_w    = (const float*)d_in[8];   // [224,224]
    const float* W_b    = (const float*)d_in[9];   // [224]
    float* out = (float*)d_out;                    // [224*224]

    float* ws = (float*)d_ws;
    float* B  = ws;            // 4*9*196 = 7056
    float* y1 = ws + 7056;     // 196
    float* y2 = ws + 7252;     // 784
    float* y3 = ws + 8036;     // 3136
    float* y4 = ws + 11172;    // 12544
    float* WT = ws + 23716;    // 50176   (total 73892 floats ~ 289 KB)

    transpose_W_kernel<<<196, 256, 0, stream>>>(W_w, WT);
    compute_B_kernel<<<784, 256, 0, stream>>>(fv, conv_w, B);

    // stage 1: H=14, h = x (no upsample)
    stage_kernel<<<1, 256, 0, stream>>>(x, 14, 0, B + 0 * 1764,
                                        conv_w, conv_b, bng, bnb, bnm, bnv, y1, 14);
    // stage 2: H=28, h = up2(y1)
    stage_kernel<<<4, 256, 0, stream>>>(y1, 14, 1, B + 1 * 1764,
                                        conv_w, conv_b, bng, bnb, bnm, bnv, y2, 28);
    // stage 3: H=56, h = up2(y2)
    stage_kernel<<<13, 256, 0, stream>>>(y2, 28, 1, B + 2 * 1764,
                                         conv_w, conv_b, bng, bnb, bnm, bnv, y3, 56);
    // stage 4: H=112, h = up2(y3)
    stage_kernel<<<49, 256, 0, stream>>>(y3, 56, 1, B + 3 * 1764,
                                         conv_w, conv_b, bng, bnb, bnm, bnv, y4, 112);

    // final: fused up2(y4) + matmul(224,224,224) + bias + sigmoid
    final_kernel<<<112, 256, 0, stream>>>(y4, WT, W_b, out);
}